// Round 18
// baseline (119.121 us; speedup 1.0000x reference)
//
#include <hip/hip_runtime.h>
#include <hip/hip_bf16.h>

typedef __attribute__((ext_vector_type(8))) short bf16x8;
typedef __attribute__((ext_vector_type(4))) short bf16x4;
typedef __attribute__((ext_vector_type(4))) float f32x4;

// ws layout (bytes):
//   WTf  [36 ct][6 ks][64 ln][8] bf16 @ 0       (221184 B)  fragment-major [Wq|Wk|Wv]
//   WfcTf[12 ct][6 ks][64 ln][8] bf16 @ 221184  (73728 B)
//   biasP[3][4 qt][4 kt][64 ln][4 jj] f32 @ 294912 (49152 B)  lane-exact, masks+pad baked

__device__ __forceinline__ short f2bf(float f) {
  __bf16 h = (__bf16)f;                       // native HW convert
  unsigned short u;
  __builtin_memcpy(&u, &h, 2);
  return (short)u;
}
// LDS anti-bank-conflict swizzle on flat short index: byte bits[6:4] ^= byte bits[9:7].
__device__ __forceinline__ int swz(int f) { return f ^ (((f >> 6) & 7) << 3); }

__global__ void prep_kernel(const float* __restrict__ Wq, const float* __restrict__ Wk,
                            const float* __restrict__ Wv, const float* __restrict__ Wfc,
                            const float* __restrict__ pos,
                            short* __restrict__ WTf, short* __restrict__ WfcTf,
                            float* __restrict__ biasP) {
  int i0 = blockIdx.x * blockDim.x + threadIdx.x;
  int stride = gridDim.x * blockDim.x;
  for (int o = i0; o < 110592; o += stride) {
    int e = o & 7, ln = (o >> 3) & 63, t = o >> 9;
    int ks = t % 6, ct = t / 6;
    int col = ct * 16 + (ln & 15);
    int k = ks * 32 + ((ln >> 4) << 3) + e;
    const float* W = (col < 192) ? Wq : (col < 384) ? Wk : Wv;
    WTf[o] = f2bf(W[k * 192 + (col % 192)]);
  }
  for (int o = i0; o < 36864; o += stride) {
    int e = o & 7, ln = (o >> 3) & 63, t = o >> 9;
    int ks = t % 6, ct = t / 6;
    int col = ct * 16 + (ln & 15);
    int k = ks * 32 + ((ln >> 4) << 3) + e;
    WfcTf[o] = f2bf(Wfc[k * 192 + col]);
  }
  // lane-exact bias table: [t][qt][kt][ln][jj] = bias(kk,qq) with -1e30 for pad/mask.
  // kk = kt*16 + (ln>>4)*4 + jj ; qq = qt*16 + (ln&15). ADD-only use in P2 is exact
  // because padded K/Q rows come from zero fragments (st=0) there.
  for (int idx = i0; idx < 12288; idx += stride) {
    int jj = idx & 3, ln = (idx >> 2) & 63, kt = (idx >> 8) & 3;
    int qt = (idx >> 10) & 3, t = idx >> 12;
    int kk = kt * 16 + ((ln >> 4) << 2) + jj;
    int qq = qt * 16 + (ln & 15);
    float v;
    if (kk >= 49 || qq >= 49) {
      v = -1e30f;
    } else {
      int ri = kk / 7 - qq / 7 + 6;
      int rj = kk % 7 - qq % 7 + 6;
      v = pos[ri * 13 + rj];
      if (t == 1 && ((qq >= 28) != (kk >= 28))) v = -1e30f;    // LOWER
      if (t == 2 && ((qq % 7 >= 4) != (kk % 7 >= 4))) v = -1e30f;  // RIGHT
    }
    biasP[idx] = v;
  }
}

__launch_bounds__(1024, 1)
__global__ void swin_fused(const float* __restrict__ x,
                           const short* __restrict__ WTf,
                           const short* __restrict__ WfcTf,
                           const float* __restrict__ biasP,
                           const float* __restrict__ bfc,
                           float* __restrict__ out) {
  // 16 waves = 2 independent 8-wave sub-groups (one 49-token g-group each).
  // LDS 124,416 B + bar, single block -> 16 waves/CU residency by construction.
  // SUB-GROUP SPIN BARRIERS decouple the two halves (R17: +3.2 us). R18: P3's
  // global weight/bias loads are hoisted ABOVE the barrier spin so their L2
  // latency overlaps the barrier wait (they don't depend on sub-LDS).
  __shared__ short qf[18816];     // [2] x q[49][192] flat (swizzled, pre-scaled sqrt32)
  __shared__ short kf[18816];     // [2] x k[49][192] flat (swizzled)
  __shared__ short vT[24576];     // [2] x per-window v^T [6][32 d][64 tok] (swizzled)
  __shared__ int   sbar[2];       // per-sub monotonic barrier counters

  const int bid = blockIdx.x;
  const int tid = threadIdx.x;
  const int wave = tid >> 6;
  const int lane = tid & 63;
  const int sub = (wave >= 8) ? 1 : 0;   // which g-group this wave serves
  const int wl = wave - sub * 8;         // wave index within sub-group [0,8)
  const int gg = bid * 2 + sub;          // global group id [0,2048)
  const int b = gg >> 6;                 // batch
  const int gl = gg & 63;                // group within batch
  const int lrow = lane & 15;            // within-tile row/col
  const int lk8 = (lane >> 4) << 3;      // k-chunk base {0,8,16,24}
  const int lg4 = (lane >> 4) << 2;      // D-frag row base {0,4,8,12}
  const int qoff = sub * 9408;
  const int voff = sub * 12288;

  const bf16x8 z8 = {0, 0, 0, 0, 0, 0, 0, 0};
  const f32x4 z4 = {0.f, 0.f, 0.f, 0.f};

  if (tid < 2) sbar[tid] = 0;
  __syncthreads();                       // once: counter init visible to all

  // sub-group barrier: 8 waves of `sub` rendezvous. Monotonic counter, targets
  // 8 (post-P1) and 16 (post-P2). DS ops are in-order per wave, so the release
  // add is ordered after this wave's prior LDS writes; acquire load orders reads.
  auto subbar = [&](int tgt) {
    if (lane == 0)
      __hip_atomic_fetch_add(&sbar[sub], 1, __ATOMIC_ACQ_REL, __HIP_MEMORY_SCOPE_WORKGROUP);
    while (__hip_atomic_load(&sbar[sub], __ATOMIC_ACQUIRE, __HIP_MEMORY_SCOPE_WORKGROUP) < tgt)
      __builtin_amdgcn_s_sleep(1);
  };

  // zero own sub's v^T token-pad (tok 49..63); disjoint from live v writes, so no
  // barrier needed here — subbar(8) covers visibility for own sub's phase 2.
  {
    const int st = tid & 511;
    for (int i = st; i < 2880; i += 512) {
      int wd = i / 15, tok = 49 + (i - wd * 15);
      vT[voff + swz(wd * 64 + tok)] = 0;
    }
  }

  // ---------------- Phase 1: QKV = x_shifted(49 tok) @ [Wq|Wk|Wv]  (M=64pad,N=576,K=192)
  // 8-wave split: mh2 = wl&1 -> row half, cw = wl>>1; BALANCED tiles ct = nt*4+cw.
  // ALL tiles operand-swapped: D^T = mfma(W, x) -> lane = fixed token, 4 consecutive cols.
  const int mh2 = wl & 1;
  const int cw = wl >> 1;
  {
    bf16x8 afrag[2][6];
    #pragma unroll
    for (int mh = 0; mh < 2; ++mh) {
      int row = mh2 * 32 + mh * 16 + lrow;
      if (row < 49) {
        int t = gl * 49 + row;
        int h = t / 56, w = t - h * 56;
        int hs = h + 3; if (hs >= 56) hs -= 56;        // roll(-3)
        int ws2 = w + 3; if (ws2 >= 56) ws2 -= 56;
        const float* xr = x + ((b * 56 + hs) * 56 + ws2) * 192 + lk8;
        #pragma unroll
        for (int ks = 0; ks < 6; ++ks) {
          float4 f0 = *(const float4*)(xr + 32 * ks);
          float4 f1 = *(const float4*)(xr + 32 * ks + 4);
          bf16x8 a;
          a[0] = f2bf(f0.x); a[1] = f2bf(f0.y); a[2] = f2bf(f0.z); a[3] = f2bf(f0.w);
          a[4] = f2bf(f1.x); a[5] = f2bf(f1.y); a[6] = f2bf(f1.z); a[7] = f2bf(f1.w);
          afrag[mh][ks] = a;
        }
      } else {
        #pragma unroll
        for (int ks = 0; ks < 6; ++ks) afrag[mh][ks] = z8;
      }
    }

    auto p1_load = [&](bf16x8 (&bfr)[6], int ct) {
      const short* wr = WTf + ct * 3072 + (lane << 3);   // coalesced 1KB/wave
      #pragma unroll
      for (int ks = 0; ks < 6; ++ks) bfr[ks] = *(const bf16x8*)(wr + ks * 512);
    };
    auto p1_tile = [&](const bf16x8 (&bfr)[6], int ct) {
      f32x4 acc0 = z4, acc1 = z4;
      __builtin_amdgcn_s_setprio(1);
      #pragma unroll
      for (int ks = 0; ks < 6; ++ks) {
        acc0 = __builtin_amdgcn_mfma_f32_16x16x32_bf16(bfr[ks], afrag[0][ks], acc0, 0, 0, 0);
        acc1 = __builtin_amdgcn_mfma_f32_16x16x32_bf16(bfr[ks], afrag[1][ks], acc1, 0, 0, 0);
      }
      __builtin_amdgcn_s_setprio(0);
      if (ct < 12) {
        int cbase = ct * 16 + lg4;
        #pragma unroll
        for (int mh = 0; mh < 2; ++mh) {
          f32x4 a4 = mh ? acc1 : acc0;
          int tok = mh2 * 32 + mh * 16 + lrow;
          if (tok < 49) {
            // fold score scale sqrt(32) into q (q only feeds QK^T)
            bf16x4 v = {f2bf(a4[0] * 5.65685424949238f), f2bf(a4[1] * 5.65685424949238f),
                        f2bf(a4[2] * 5.65685424949238f), f2bf(a4[3] * 5.65685424949238f)};
            *(bf16x4*)(qf + qoff + swz(tok * 192 + cbase)) = v;
          }
        }
      } else if (ct < 24) {
        int cbase = (ct - 12) * 16 + lg4;
        #pragma unroll
        for (int mh = 0; mh < 2; ++mh) {
          f32x4 a4 = mh ? acc1 : acc0;
          int tok = mh2 * 32 + mh * 16 + lrow;
          if (tok < 49) {
            bf16x4 v = {f2bf(a4[0]), f2bf(a4[1]), f2bf(a4[2]), f2bf(a4[3])};
            *(bf16x4*)(kf + qoff + swz(tok * 192 + cbase)) = v;
          }
        }
      } else {
        int cbase = (ct - 24) * 16 + lg4;
        #pragma unroll
        for (int mh = 0; mh < 2; ++mh) {
          f32x4 a4 = mh ? acc1 : acc0;
          int tok = mh2 * 32 + mh * 16 + lrow;
          if (tok < 49) {
            int flat0 = tok * 192 + cbase;          // quad stays in one window (1568%4==0)
            int w2 = flat0 / 1568;
            int rem0 = flat0 - w2 * 1568;
            int base0 = (w2 * 32 + (rem0 & 31)) * 64 + (rem0 >> 5);
            vT[voff + swz(base0)]       = f2bf(a4[0]);
            vT[voff + swz(base0 + 64)]  = f2bf(a4[1]);
            vT[voff + swz(base0 + 128)] = f2bf(a4[2]);
            vT[voff + swz(base0 + 192)] = f2bf(a4[3]);
          }
        }
      }
    };

    bf16x8 bA[6], bB[6];
    p1_load(bA, cw);                                     // ct(nt) = nt*4 + cw
    #pragma unroll 1
    for (int nt = 0; nt < 8; nt += 2) {
      p1_load(bB, (nt + 1) * 4 + cw);
      p1_tile(bA, nt * 4 + cw);
      if (nt + 2 < 9) p1_load(bA, (nt + 2) * 4 + cw);
      p1_tile(bB, (nt + 1) * 4 + cw);
    }
    p1_tile(bA, 32 + cw);
  }
  subbar(8);                             // own sub's P1 complete

  // ---------------- Phase 2: attention. 24 (window,qt) units / 8 waves = 3 each.
  // Swapped QK^T: S^T = mfma(K, Q); bias via 4 coalesced float4 loads issued BEFORE
  // the MFMAs; streaming softmax; va loaded AFTER softmax (frees 16 regs at peak).
  #pragma unroll 1
  for (int u3 = 0; u3 < 3; ++u3) {
    int u = wl * 3 + u3;
    int win = u >> 2, qt = u & 3;
    int qbase = win * 1568;
    int gwin = (gl * 6 + win) & 63;
    int tsel = (gwin >= 56) ? 1 : (gwin == 7) ? 2 : 0;

    // bias prefetch: [t][qt][kt][ln][jj] -> 4 coalesced dwordx4 per unit
    const float* bp = biasP + ((tsel * 4 + qt) * 4) * 256 + (lane << 2);
    f32x4 bv[4];
    #pragma unroll
    for (int kt = 0; kt < 4; ++kt)
      bv[kt] = *(const f32x4*)(bp + kt * 256);

    bf16x8 ka[4];
    #pragma unroll
    for (int kt = 0; kt < 4; ++kt) {
      int row = kt * 16 + lrow;
      ka[kt] = (row < 49) ? *(const bf16x8*)(kf + qoff + swz(qbase + row * 32 + lk8)) : z8;
    }

    int qq = qt * 16 + lrow;
    bf16x8 qb = (qq < 49) ? *(const bf16x8*)(qf + qoff + swz(qbase + qq * 32 + lk8)) : z8;
    f32x4 st[4];
    __builtin_amdgcn_s_setprio(1);
    #pragma unroll
    for (int kt = 0; kt < 4; ++kt)
      st[kt] = __builtin_amdgcn_mfma_f32_16x16x32_bf16(ka[kt], qb, z4, 0, 0, 0);
    __builtin_amdgcn_s_setprio(0);

    // add-only bias (pad rows are zero-fragments -> 0 + (-1e30) = masked)
    #pragma unroll
    for (int kt = 0; kt < 4; ++kt)
      #pragma unroll
      for (int jj = 0; jj < 4; ++jj)
        st[kt][jj] += bv[kt][jj];

    float m = -1e30f;
    #pragma unroll
    for (int kt = 0; kt < 4; ++kt)
      #pragma unroll
      for (int jj = 0; jj < 4; ++jj) m = fmaxf(m, st[kt][jj]);
    m = fmaxf(m, __shfl_xor(m, 16));
    m = fmaxf(m, __shfl_xor(m, 32));
    float sum = 0.f;
    #pragma unroll
    for (int kt = 0; kt < 4; ++kt)
      #pragma unroll
      for (int jj = 0; jj < 4; ++jj) {
        float e = __expf(st[kt][jj] - m);
        st[kt][jj] = e;
        sum += e;
      }
    sum += __shfl_xor(sum, 16);
    sum += __shfl_xor(sum, 32);
    float inv = 1.0f / sum;
    bf16x4 pb[4];
    #pragma unroll
    for (int kt = 0; kt < 4; ++kt) {
      bf16x4 p = {f2bf(st[kt][0] * inv), f2bf(st[kt][1] * inv),
                  f2bf(st[kt][2] * inv), f2bf(st[kt][3] * inv)};
      pb[kt] = p;
    }

    // va loaded here (post-softmax): 8 back-to-back b64 reads, only first-use
    // latency exposed; frees 16 VGPRs during the softmax pressure peak.
    bf16x4 va[2][4];
    #pragma unroll
    for (int dt = 0; dt < 2; ++dt)
      #pragma unroll
      for (int kt = 0; kt < 4; ++kt)
        va[dt][kt] = *(const bf16x4*)(vT + voff + swz((win * 32 + dt * 16 + lrow) * 64 + kt * 16 + lg4));

    // PV for this unit, immediate writeback. Unit regions are disjoint; same-wave
    // DS ops execute in issue order (qb consumed via reg deps before the write).
    #pragma unroll
    for (int dt = 0; dt < 2; ++dt) {
      f32x4 oo = z4;
#if __has_builtin(__builtin_amdgcn_mfma_f32_16x16x16bf16_1k)
      #pragma unroll
      for (int kt = 0; kt < 4; ++kt)
        oo = __builtin_amdgcn_mfma_f32_16x16x16bf16_1k(va[dt][kt], pb[kt], oo, 0, 0, 0);
#else
      #pragma unroll
      for (int kt = 0; kt < 4; ++kt) {
        bf16x8 va8 = {va[dt][kt][0], va[dt][kt][1], va[dt][kt][2], va[dt][kt][3], 0, 0, 0, 0};
        bf16x8 pb8 = {pb[kt][0], pb[kt][1], pb[kt][2], pb[kt][3], 0, 0, 0, 0};
        oo = __builtin_amdgcn_mfma_f32_16x16x32_bf16(va8, pb8, oo, 0, 0, 0);
      }
#endif
      if (qq < 49) {
        bf16x4 ov = {f2bf(oo[0]), f2bf(oo[1]), f2bf(oo[2]), f2bf(oo[3])};
        *(bf16x4*)(qf + qoff + swz(qbase + qq * 32 + dt * 16 + lg4)) = ov;
      }
    }
  }

  // ---------------- Phase 3 prologue BEFORE the barrier: global weight/bias loads
  // (WfcTf, bfc are constant weights — independent of sub-LDS state), so their L2
  // latency overlaps the subbar(16) spin wait. +24 regs here, but P2's working set
  // is dead at this point (pressure trough).
  const int wq = wl >> 1;
  bf16x8 wA[3], wB[3];
  #pragma unroll
  for (int nc = 0; nc < 3; ++nc)
    wA[nc] = *(const bf16x8*)(WfcTf + ((wq * 3 + nc) * 6 + 0) * 512 + (lane << 3));
  const int colb = wq * 48 + lg4;
  f32x4 bias[3];
  #pragma unroll
  for (int nc = 0; nc < 3; ++nc)
    bias[nc] = *(const f32x4*)(bfc + colb + nc * 16);

  subbar(16);                            // own sub's P2 complete

  // ---------------- Phase 3: out = attnout[49][192] @ Wfc + bfc, inverse roll
  // OPERAND-SWAPPED: acc^T = mfma(Wfc, oa) -> lane: fixed token (lrow), 4 consecutive
  // out-cols per reg quad -> float4 global stores + roll addressing once per mi.
  {
    f32x4 acc[2][3];
    #pragma unroll
    for (int mi = 0; mi < 2; ++mi)
      #pragma unroll
      for (int nc = 0; nc < 3; ++nc) acc[mi][nc] = z4;

    auto p3_load = [&](bf16x8 (&wf)[3], int ks) {
      #pragma unroll
      for (int nc = 0; nc < 3; ++nc)
        wf[nc] = *(const bf16x8*)(WfcTf + ((wq * 3 + nc) * 6 + ks) * 512 + (lane << 3));
    };
    auto p3_step = [&](const bf16x8 (&wf)[3], int ks) {
      bf16x8 oa[2];
      #pragma unroll
      for (int mi = 0; mi < 2; ++mi) {
        int row = mh2 * 32 + mi * 16 + lrow;
        oa[mi] = (row < 49) ? *(const bf16x8*)(qf + qoff + swz(row * 192 + ks * 32 + lk8)) : z8;
      }
      __builtin_amdgcn_s_setprio(1);
      #pragma unroll
      for (int nc = 0; nc < 3; ++nc)
        #pragma unroll
        for (int mi = 0; mi < 2; ++mi)
          acc[mi][nc] = __builtin_amdgcn_mfma_f32_16x16x32_bf16(wf[nc], oa[mi], acc[mi][nc], 0, 0, 0);
      __builtin_amdgcn_s_setprio(0);
    };

    #pragma unroll 1
    for (int ks = 0; ks < 6; ks += 2) {
      p3_load(wB, ks + 1);
      p3_step(wA, ks);
      if (ks + 2 < 6) p3_load(wA, ks + 2);
      p3_step(wB, ks + 1);
    }

    // cols wq*48 + nc*16 + lg4 + jj (jj consecutive) -> float4 stores, roll once per mi
    #pragma unroll
    for (int mi = 0; mi < 2; ++mi) {
      int tok = mh2 * 32 + mi * 16 + lrow;
      if (tok < 49) {
        int t = gl * 49 + tok;
        int h = t / 56, w = t - h * 56;
        int hd = h + 3; if (hd >= 56) hd -= 56;    // roll(+3)
        int wd = w + 3; if (wd >= 56) wd -= 56;
        float* orow = out + (size_t)((b * 56 + hd) * 56 + wd) * 192 + colb;
        #pragma unroll
        for (int nc = 0; nc < 3; ++nc) {
          f32x4 v = acc[mi][nc] + bias[nc];
          *(f32x4*)(orow + nc * 16) = v;
        }
      }
    }
  }
}

extern "C" void kernel_launch(void* const* d_in, const int* in_sizes, int n_in,
                              void* d_out, int out_size, void* d_ws, size_t ws_size,
                              hipStream_t stream) {
  const float* x   = (const float*)d_in[0];
  const float* Wq  = (const float*)d_in[1];
  const float* Wk  = (const float*)d_in[2];
  const float* Wv  = (const float*)d_in[3];
  const float* Wfc = (const float*)d_in[4];
  const float* bfc = (const float*)d_in[5];
  const float* pos = (const float*)d_in[6];

  short* WTf   = (short*)d_ws;
  short* WfcTf = (short*)((char*)d_ws + 221184);
  float* biasP = (float*)((char*)d_ws + 294912);

  hipLaunchKernelGGL(prep_kernel, dim3(128), dim3(256), 0, stream,
                     Wq, Wk, Wv, Wfc, pos, WTf, WfcTf, biasP);
  hipLaunchKernelGGL(swin_fused, dim3(1024), dim3(1024), 0, stream,
                     x, WTf, WfcTf, biasP, bfc, (float*)d_out);
}

// Round 19
// 115.760 us; speedup vs baseline: 1.0290x; 1.0290x over previous
//
#include <hip/hip_runtime.h>
#include <hip/hip_bf16.h>

typedef __attribute__((ext_vector_type(8))) short bf16x8;
typedef __attribute__((ext_vector_type(4))) short bf16x4;
typedef __attribute__((ext_vector_type(4))) float f32x4;

// ws layout (bytes):
//   WTf  [36 ct][6 ks][64 ln][8] bf16 @ 0       (221184 B)  fragment-major [Wq|Wk|Wv]
//   WfcTf[12 ct][6 ks][64 ln][8] bf16 @ 221184  (73728 B)
//   biasP[3][4 qt][4 kt][64 ln][4 jj] f32 @ 294912 (49152 B)  lane-exact, masks+pad baked

__device__ __forceinline__ short f2bf(float f) {
  __bf16 h = (__bf16)f;                       // native HW convert
  unsigned short u;
  __builtin_memcpy(&u, &h, 2);
  return (short)u;
}
// LDS anti-bank-conflict swizzle on flat short index: byte bits[6:4] ^= byte bits[9:7].
__device__ __forceinline__ int swz(int f) { return f ^ (((f >> 6) & 7) << 3); }

__global__ void prep_kernel(const float* __restrict__ Wq, const float* __restrict__ Wk,
                            const float* __restrict__ Wv, const float* __restrict__ Wfc,
                            const float* __restrict__ pos,
                            short* __restrict__ WTf, short* __restrict__ WfcTf,
                            float* __restrict__ biasP) {
  int i0 = blockIdx.x * blockDim.x + threadIdx.x;
  int stride = gridDim.x * blockDim.x;
  for (int o = i0; o < 110592; o += stride) {
    int e = o & 7, ln = (o >> 3) & 63, t = o >> 9;
    int ks = t % 6, ct = t / 6;
    int col = ct * 16 + (ln & 15);
    int k = ks * 32 + ((ln >> 4) << 3) + e;
    const float* W = (col < 192) ? Wq : (col < 384) ? Wk : Wv;
    WTf[o] = f2bf(W[k * 192 + (col % 192)]);
  }
  for (int o = i0; o < 36864; o += stride) {
    int e = o & 7, ln = (o >> 3) & 63, t = o >> 9;
    int ks = t % 6, ct = t / 6;
    int col = ct * 16 + (ln & 15);
    int k = ks * 32 + ((ln >> 4) << 3) + e;
    WfcTf[o] = f2bf(Wfc[k * 192 + col]);
  }
  // lane-exact bias table: [t][qt][kt][ln][jj] = bias(kk,qq) with -1e30 for pad/mask.
  // kk = kt*16 + (ln>>4)*4 + jj ; qq = qt*16 + (ln&15). ADD-only use in P2 is exact
  // because padded K/Q rows come from zero fragments (st=0) there.
  for (int idx = i0; idx < 12288; idx += stride) {
    int jj = idx & 3, ln = (idx >> 2) & 63, kt = (idx >> 8) & 3;
    int qt = (idx >> 10) & 3, t = idx >> 12;
    int kk = kt * 16 + ((ln >> 4) << 2) + jj;
    int qq = qt * 16 + (ln & 15);
    float v;
    if (kk >= 49 || qq >= 49) {
      v = -1e30f;
    } else {
      int ri = kk / 7 - qq / 7 + 6;
      int rj = kk % 7 - qq % 7 + 6;
      v = pos[ri * 13 + rj];
      if (t == 1 && ((qq >= 28) != (kk >= 28))) v = -1e30f;    // LOWER
      if (t == 2 && ((qq % 7 >= 4) != (kk % 7 >= 4))) v = -1e30f;  // RIGHT
    }
    biasP[idx] = v;
  }
}

__launch_bounds__(1024, 1)
__global__ void swin_fused(const float* __restrict__ x,
                           const short* __restrict__ WTf,
                           const short* __restrict__ WfcTf,
                           const float* __restrict__ biasP,
                           const float* __restrict__ bfc,
                           float* __restrict__ out) {
  // 16 waves = 2 independent 8-wave sub-groups (one 49-token g-group each).
  // LDS 124,416 B + bar, single block -> 16 waves/CU residency by construction.
  // SUB-GROUP SPIN BARRIERS decouple the two halves: each sub syncs only its own
  // 8 waves, so the subs can slip in phase (MFMA-heavy P1 of one overlapping the
  // VALU-heavy softmax of the other) instead of contending for the same pipe.
  // NOTE (R14/R18 lesson): at the immovable 64-VGPR cap, do NOT hoist loads
  // across phase boundaries — extending live ranges there is net-negative.
  __shared__ short qf[18816];     // [2] x q[49][192] flat (swizzled, pre-scaled sqrt32)
  __shared__ short kf[18816];     // [2] x k[49][192] flat (swizzled)
  __shared__ short vT[24576];     // [2] x per-window v^T [6][32 d][64 tok] (swizzled)
  __shared__ int   sbar[2];       // per-sub monotonic barrier counters

  const int bid = blockIdx.x;
  const int tid = threadIdx.x;
  const int wave = tid >> 6;
  const int lane = tid & 63;
  const int sub = (wave >= 8) ? 1 : 0;   // which g-group this wave serves
  const int wl = wave - sub * 8;         // wave index within sub-group [0,8)
  const int gg = bid * 2 + sub;          // global group id [0,2048)
  const int b = gg >> 6;                 // batch
  const int gl = gg & 63;                // group within batch
  const int lrow = lane & 15;            // within-tile row/col
  const int lk8 = (lane >> 4) << 3;      // k-chunk base {0,8,16,24}
  const int lg4 = (lane >> 4) << 2;      // D-frag row base {0,4,8,12}
  const int qoff = sub * 9408;
  const int voff = sub * 12288;

  const bf16x8 z8 = {0, 0, 0, 0, 0, 0, 0, 0};
  const f32x4 z4 = {0.f, 0.f, 0.f, 0.f};

  if (tid < 2) sbar[tid] = 0;
  __syncthreads();                       // once: counter init visible to all

  // sub-group barrier: 8 waves of `sub` rendezvous. Monotonic counter, targets
  // 8 (post-P1) and 16 (post-P2). DS ops are in-order per wave, so the release
  // add is ordered after this wave's prior LDS writes; acquire load orders reads.
  auto subbar = [&](int tgt) {
    if (lane == 0)
      __hip_atomic_fetch_add(&sbar[sub], 1, __ATOMIC_ACQ_REL, __HIP_MEMORY_SCOPE_WORKGROUP);
    while (__hip_atomic_load(&sbar[sub], __ATOMIC_ACQUIRE, __HIP_MEMORY_SCOPE_WORKGROUP) < tgt)
      __builtin_amdgcn_s_sleep(1);
  };

  // zero own sub's v^T token-pad (tok 49..63); disjoint from live v writes, so no
  // barrier needed here — subbar(8) covers visibility for own sub's phase 2.
  {
    const int st = tid & 511;
    for (int i = st; i < 2880; i += 512) {
      int wd = i / 15, tok = 49 + (i - wd * 15);
      vT[voff + swz(wd * 64 + tok)] = 0;
    }
  }

  // ---------------- Phase 1: QKV = x_shifted(49 tok) @ [Wq|Wk|Wv]  (M=64pad,N=576,K=192)
  // 8-wave split: mh2 = wl&1 -> row half, cw = wl>>1; BALANCED tiles ct = nt*4+cw.
  // ALL tiles operand-swapped: D^T = mfma(W, x) -> lane = fixed token, 4 consecutive cols.
  const int mh2 = wl & 1;
  const int cw = wl >> 1;
  {
    bf16x8 afrag[2][6];
    #pragma unroll
    for (int mh = 0; mh < 2; ++mh) {
      int row = mh2 * 32 + mh * 16 + lrow;
      if (row < 49) {
        int t = gl * 49 + row;
        int h = t / 56, w = t - h * 56;
        int hs = h + 3; if (hs >= 56) hs -= 56;        // roll(-3)
        int ws2 = w + 3; if (ws2 >= 56) ws2 -= 56;
        const float* xr = x + ((b * 56 + hs) * 56 + ws2) * 192 + lk8;
        #pragma unroll
        for (int ks = 0; ks < 6; ++ks) {
          float4 f0 = *(const float4*)(xr + 32 * ks);
          float4 f1 = *(const float4*)(xr + 32 * ks + 4);
          bf16x8 a;
          a[0] = f2bf(f0.x); a[1] = f2bf(f0.y); a[2] = f2bf(f0.z); a[3] = f2bf(f0.w);
          a[4] = f2bf(f1.x); a[5] = f2bf(f1.y); a[6] = f2bf(f1.z); a[7] = f2bf(f1.w);
          afrag[mh][ks] = a;
        }
      } else {
        #pragma unroll
        for (int ks = 0; ks < 6; ++ks) afrag[mh][ks] = z8;
      }
    }

    auto p1_load = [&](bf16x8 (&bfr)[6], int ct) {
      const short* wr = WTf + ct * 3072 + (lane << 3);   // coalesced 1KB/wave
      #pragma unroll
      for (int ks = 0; ks < 6; ++ks) bfr[ks] = *(const bf16x8*)(wr + ks * 512);
    };
    auto p1_tile = [&](const bf16x8 (&bfr)[6], int ct) {
      f32x4 acc0 = z4, acc1 = z4;
      __builtin_amdgcn_s_setprio(1);
      #pragma unroll
      for (int ks = 0; ks < 6; ++ks) {
        acc0 = __builtin_amdgcn_mfma_f32_16x16x32_bf16(bfr[ks], afrag[0][ks], acc0, 0, 0, 0);
        acc1 = __builtin_amdgcn_mfma_f32_16x16x32_bf16(bfr[ks], afrag[1][ks], acc1, 0, 0, 0);
      }
      __builtin_amdgcn_s_setprio(0);
      if (ct < 12) {
        int cbase = ct * 16 + lg4;
        #pragma unroll
        for (int mh = 0; mh < 2; ++mh) {
          f32x4 a4 = mh ? acc1 : acc0;
          int tok = mh2 * 32 + mh * 16 + lrow;
          if (tok < 49) {
            // fold score scale sqrt(32) into q (q only feeds QK^T)
            bf16x4 v = {f2bf(a4[0] * 5.65685424949238f), f2bf(a4[1] * 5.65685424949238f),
                        f2bf(a4[2] * 5.65685424949238f), f2bf(a4[3] * 5.65685424949238f)};
            *(bf16x4*)(qf + qoff + swz(tok * 192 + cbase)) = v;
          }
        }
      } else if (ct < 24) {
        int cbase = (ct - 12) * 16 + lg4;
        #pragma unroll
        for (int mh = 0; mh < 2; ++mh) {
          f32x4 a4 = mh ? acc1 : acc0;
          int tok = mh2 * 32 + mh * 16 + lrow;
          if (tok < 49) {
            bf16x4 v = {f2bf(a4[0]), f2bf(a4[1]), f2bf(a4[2]), f2bf(a4[3])};
            *(bf16x4*)(kf + qoff + swz(tok * 192 + cbase)) = v;
          }
        }
      } else {
        int cbase = (ct - 24) * 16 + lg4;
        #pragma unroll
        for (int mh = 0; mh < 2; ++mh) {
          f32x4 a4 = mh ? acc1 : acc0;
          int tok = mh2 * 32 + mh * 16 + lrow;
          if (tok < 49) {
            int flat0 = tok * 192 + cbase;          // quad stays in one window (1568%4==0)
            int w2 = flat0 / 1568;
            int rem0 = flat0 - w2 * 1568;
            int base0 = (w2 * 32 + (rem0 & 31)) * 64 + (rem0 >> 5);
            vT[voff + swz(base0)]       = f2bf(a4[0]);
            vT[voff + swz(base0 + 64)]  = f2bf(a4[1]);
            vT[voff + swz(base0 + 128)] = f2bf(a4[2]);
            vT[voff + swz(base0 + 192)] = f2bf(a4[3]);
          }
        }
      }
    };

    bf16x8 bA[6], bB[6];
    p1_load(bA, cw);                                     // ct(nt) = nt*4 + cw
    #pragma unroll 1
    for (int nt = 0; nt < 8; nt += 2) {
      p1_load(bB, (nt + 1) * 4 + cw);
      p1_tile(bA, nt * 4 + cw);
      if (nt + 2 < 9) p1_load(bA, (nt + 2) * 4 + cw);
      p1_tile(bB, (nt + 1) * 4 + cw);
    }
    p1_tile(bA, 32 + cw);
  }
  subbar(8);                             // own sub's P1 complete

  // ---------------- Phase 2: attention. 24 (window,qt) units / 8 waves = 3 each.
  // Swapped QK^T: S^T = mfma(K, Q); bias via 4 coalesced float4 loads issued BEFORE
  // the MFMAs; streaming softmax; va loaded AFTER softmax (frees 16 regs at peak).
  #pragma unroll 1
  for (int u3 = 0; u3 < 3; ++u3) {
    int u = wl * 3 + u3;
    int win = u >> 2, qt = u & 3;
    int qbase = win * 1568;
    int gwin = (gl * 6 + win) & 63;
    int tsel = (gwin >= 56) ? 1 : (gwin == 7) ? 2 : 0;

    // bias prefetch: [t][qt][kt][ln][jj] -> 4 coalesced dwordx4 per unit
    const float* bp = biasP + ((tsel * 4 + qt) * 4) * 256 + (lane << 2);
    f32x4 bv[4];
    #pragma unroll
    for (int kt = 0; kt < 4; ++kt)
      bv[kt] = *(const f32x4*)(bp + kt * 256);

    bf16x8 ka[4];
    #pragma unroll
    for (int kt = 0; kt < 4; ++kt) {
      int row = kt * 16 + lrow;
      ka[kt] = (row < 49) ? *(const bf16x8*)(kf + qoff + swz(qbase + row * 32 + lk8)) : z8;
    }

    int qq = qt * 16 + lrow;
    bf16x8 qb = (qq < 49) ? *(const bf16x8*)(qf + qoff + swz(qbase + qq * 32 + lk8)) : z8;
    f32x4 st[4];
    __builtin_amdgcn_s_setprio(1);
    #pragma unroll
    for (int kt = 0; kt < 4; ++kt)
      st[kt] = __builtin_amdgcn_mfma_f32_16x16x32_bf16(ka[kt], qb, z4, 0, 0, 0);
    __builtin_amdgcn_s_setprio(0);

    // add-only bias (pad rows are zero-fragments -> 0 + (-1e30) = masked)
    #pragma unroll
    for (int kt = 0; kt < 4; ++kt)
      #pragma unroll
      for (int jj = 0; jj < 4; ++jj)
        st[kt][jj] += bv[kt][jj];

    float m = -1e30f;
    #pragma unroll
    for (int kt = 0; kt < 4; ++kt)
      #pragma unroll
      for (int jj = 0; jj < 4; ++jj) m = fmaxf(m, st[kt][jj]);
    m = fmaxf(m, __shfl_xor(m, 16));
    m = fmaxf(m, __shfl_xor(m, 32));
    float sum = 0.f;
    #pragma unroll
    for (int kt = 0; kt < 4; ++kt)
      #pragma unroll
      for (int jj = 0; jj < 4; ++jj) {
        float e = __expf(st[kt][jj] - m);
        st[kt][jj] = e;
        sum += e;
      }
    sum += __shfl_xor(sum, 16);
    sum += __shfl_xor(sum, 32);
    float inv = 1.0f / sum;
    bf16x4 pb[4];
    #pragma unroll
    for (int kt = 0; kt < 4; ++kt) {
      bf16x4 p = {f2bf(st[kt][0] * inv), f2bf(st[kt][1] * inv),
                  f2bf(st[kt][2] * inv), f2bf(st[kt][3] * inv)};
      pb[kt] = p;
    }

    // va loaded here (post-softmax): 8 back-to-back b64 reads, only first-use
    // latency exposed; frees 16 VGPRs during the softmax pressure peak.
    bf16x4 va[2][4];
    #pragma unroll
    for (int dt = 0; dt < 2; ++dt)
      #pragma unroll
      for (int kt = 0; kt < 4; ++kt)
        va[dt][kt] = *(const bf16x4*)(vT + voff + swz((win * 32 + dt * 16 + lrow) * 64 + kt * 16 + lg4));

    // PV for this unit, immediate writeback. Unit regions are disjoint; same-wave
    // DS ops execute in issue order (qb consumed via reg deps before the write).
    #pragma unroll
    for (int dt = 0; dt < 2; ++dt) {
      f32x4 oo = z4;
#if __has_builtin(__builtin_amdgcn_mfma_f32_16x16x16bf16_1k)
      #pragma unroll
      for (int kt = 0; kt < 4; ++kt)
        oo = __builtin_amdgcn_mfma_f32_16x16x16bf16_1k(va[dt][kt], pb[kt], oo, 0, 0, 0);
#else
      #pragma unroll
      for (int kt = 0; kt < 4; ++kt) {
        bf16x8 va8 = {va[dt][kt][0], va[dt][kt][1], va[dt][kt][2], va[dt][kt][3], 0, 0, 0, 0};
        bf16x8 pb8 = {pb[kt][0], pb[kt][1], pb[kt][2], pb[kt][3], 0, 0, 0, 0};
        oo = __builtin_amdgcn_mfma_f32_16x16x32_bf16(va8, pb8, oo, 0, 0, 0);
      }
#endif
      if (qq < 49) {
        bf16x4 ov = {f2bf(oo[0]), f2bf(oo[1]), f2bf(oo[2]), f2bf(oo[3])};
        *(bf16x4*)(qf + qoff + swz(qbase + qq * 32 + dt * 16 + lg4)) = ov;
      }
    }
  }
  subbar(16);                            // own sub's P2 complete

  // ---------------- Phase 3: out = attnout[49][192] @ Wfc + bfc, inverse roll
  // OPERAND-SWAPPED: acc^T = mfma(Wfc, oa) -> lane: fixed token (lrow), 4 consecutive
  // out-cols per reg quad -> float4 global stores + roll addressing once per mi.
  {
    const int wq = wl >> 1;
    f32x4 acc[2][3];
    #pragma unroll
    for (int mi = 0; mi < 2; ++mi)
      #pragma unroll
      for (int nc = 0; nc < 3; ++nc) acc[mi][nc] = z4;

    auto p3_load = [&](bf16x8 (&wf)[3], int ks) {
      #pragma unroll
      for (int nc = 0; nc < 3; ++nc)
        wf[nc] = *(const bf16x8*)(WfcTf + ((wq * 3 + nc) * 6 + ks) * 512 + (lane << 3));
    };
    auto p3_step = [&](const bf16x8 (&wf)[3], int ks) {
      bf16x8 oa[2];
      #pragma unroll
      for (int mi = 0; mi < 2; ++mi) {
        int row = mh2 * 32 + mi * 16 + lrow;
        oa[mi] = (row < 49) ? *(const bf16x8*)(qf + qoff + swz(row * 192 + ks * 32 + lk8)) : z8;
      }
      __builtin_amdgcn_s_setprio(1);
      #pragma unroll
      for (int nc = 0; nc < 3; ++nc)
        #pragma unroll
        for (int mi = 0; mi < 2; ++mi)
          acc[mi][nc] = __builtin_amdgcn_mfma_f32_16x16x32_bf16(wf[nc], oa[mi], acc[mi][nc], 0, 0, 0);
      __builtin_amdgcn_s_setprio(0);
    };

    bf16x8 wA[3], wB[3];
    p3_load(wA, 0);
    #pragma unroll 1
    for (int ks = 0; ks < 6; ks += 2) {
      p3_load(wB, ks + 1);
      p3_step(wA, ks);
      if (ks + 2 < 6) p3_load(wA, ks + 2);
      p3_step(wB, ks + 1);
    }

    // cols wq*48 + nc*16 + lg4 + jj (jj consecutive) -> float4 bias loads + stores
    const int colb = wq * 48 + lg4;
    f32x4 bias[3];
    #pragma unroll
    for (int nc = 0; nc < 3; ++nc)
      bias[nc] = *(const f32x4*)(bfc + colb + nc * 16);
    #pragma unroll
    for (int mi = 0; mi < 2; ++mi) {
      int tok = mh2 * 32 + mi * 16 + lrow;
      if (tok < 49) {
        int t = gl * 49 + tok;
        int h = t / 56, w = t - h * 56;
        int hd = h + 3; if (hd >= 56) hd -= 56;    // roll(+3)
        int wd = w + 3; if (wd >= 56) wd -= 56;
        float* orow = out + (size_t)((b * 56 + hd) * 56 + wd) * 192 + colb;
        #pragma unroll
        for (int nc = 0; nc < 3; ++nc) {
          f32x4 v = acc[mi][nc] + bias[nc];
          *(f32x4*)(orow + nc * 16) = v;
        }
      }
    }
  }
}

extern "C" void kernel_launch(void* const* d_in, const int* in_sizes, int n_in,
                              void* d_out, int out_size, void* d_ws, size_t ws_size,
                              hipStream_t stream) {
  const float* x   = (const float*)d_in[0];
  const float* Wq  = (const float*)d_in[1];
  const float* Wk  = (const float*)d_in[2];
  const float* Wv  = (const float*)d_in[3];
  const float* Wfc = (const float*)d_in[4];
  const float* bfc = (const float*)d_in[5];
  const float* pos = (const float*)d_in[6];

  short* WTf   = (short*)d_ws;
  short* WfcTf = (short*)((char*)d_ws + 221184);
  float* biasP = (float*)((char*)d_ws + 294912);

  hipLaunchKernelGGL(prep_kernel, dim3(128), dim3(256), 0, stream,
                     Wq, Wk, Wv, Wfc, pos, WTf, WfcTf, biasP);
  hipLaunchKernelGGL(swin_fused, dim3(1024), dim3(1024), 0, stream,
                     x, WTf, WfcTf, biasP, bfc, (float*)d_out);
}